// Round 15
// baseline (672.007 us; speedup 1.0000x reference)
//
#include <hip/hip_runtime.h>

// Fused Conv1d(k=3,pad=1) + BN(inference) + 4-step LIF + residual.
// x: (L=2048, TB=128, D=128) f32. conv_w: (D,D,3). out: (L,TB,D) f32.
//
// R17 = R16 (double-buffered ws, 1 barrier/tile, chunked xs, R7 inner loop)
// with a T-PAIR tile loop: conv for two t's per pass, sharing each W
// fragment read across both (24 W ds_reads -> 1536 thread-FMAs, was 768).
// Tile loop runs 32x instead of 64x -> barriers 73 -> ~38 (R16 measured
// ~1.7k cyc/barrier). LIF stays sequential in the epilogue (v in regs,
// lambda with static acc refs — no runtime-indexed arrays). launch_bounds
// (256,2): non-clamping VGPR cap for the ~150-reg working set.
// Per-(o,l,t) FMA order bit-identical to R3/R7/R16 (absmax must stay 0.0).

constexpr int L   = 2048;
constexpr int NTB = 128;
constexpr int D   = 128;
constexpr int T   = 4;
constexpr int LT  = 64;        // l-tile per block
constexpr int NP  = LT + 2;    // 66 staged positions (halo)
constexpr int JT  = 8;         // l-positions per thread (2 groups x 8 per wave)

__global__ __launch_bounds__(256, 2)
void snn_conv_lif(const float* __restrict__ x, const float* __restrict__ w,
                  const float* __restrict__ gamma, const float* __restrict__ beta,
                  const float* __restrict__ mean, const float* __restrict__ var,
                  float* __restrict__ out) {
    __shared__ float xs[2][NP * 16 * 4];   // 2 x 16896 B: 64-ch chunk per n
    __shared__ float ws[2][768 * 4];       // 2 x 12288 B: dbuf weight tile
                                           // total 58368 B

    const int tid = threadIdx.x;
    const int b   = blockIdx.x & 31;
    const int lt  = blockIdx.x >> 5;
    const int l0  = lt * LT;
    const int q4  = tid & 31;                                 // o-quad
    const int p0  = (tid >> 6) * 16 + ((tid >> 5) & 1) * JT;  // l-group base
    const float4* x4 = (const float4*)x;

    // per-thread staging map (same transposed layout as R7/R16)
    int wgoff[3], wloff[3];
    #pragma unroll
    for (int r = 0; r < 3; ++r) {
        const int idx = tid + r * 256;
        const int qq  = idx & 31;
        const int cc  = idx >> 5;          // 0..23
        const int f   = cc >> 2;           // 0..5
        const int oo  = cc & 3;            // 0..3
        wgoff[r] = (4 * qq + oo) * (D * 3) + f * 4;          // + it*24
        wloff[r] = ((oo * 6 + f) * 32 + qq) * 4;
    }

    float sc[4], bi[4];
    {
        const float4 g4 = ((const float4*)gamma)[q4];
        const float4 b4 = ((const float4*)beta)[q4];
        const float4 m4 = ((const float4*)mean)[q4];
        const float4 v4 = ((const float4*)var)[q4];
        const float gg[4] = {g4.x, g4.y, g4.z, g4.w};
        const float bb[4] = {b4.x, b4.y, b4.z, b4.w};
        const float mm[4] = {m4.x, m4.y, m4.z, m4.w};
        const float vv[4] = {v4.x, v4.y, v4.z, v4.w};
        #pragma unroll
        for (int oo = 0; oo < 4; ++oo) {
            sc[oo] = gg[oo] / sqrtf(vv[oo] + 1e-5f);
            bi[oo] = bb[oo] - mm[oo] * sc[oo];
        }
    }

    float v[4][JT];
    #pragma unroll
    for (int oo = 0; oo < 4; ++oo)
        #pragma unroll
        for (int j = 0; j < JT; ++j) v[oo][j] = 0.f;

    // ---- prologue: stage weight tile 0 into buf 0 ----
    #pragma unroll
    for (int r = 0; r < 3; ++r)
        *((float4*)(&ws[0][wloff[r]])) = *((const float4*)(w + wgoff[r]));

    // epilogue helper: BN + LIF step for one t from one acc array (static refs)
    auto epi = [&](const float (&a)[4][JT], int t) {
        const int n = t * 32 + b;
        #pragma unroll
        for (int j = 0; j < JT; ++j) {
            const int l = l0 + p0 + j;
            const float4 res = x4[(l * NTB + n) * 32 + q4];
            const float rr[4] = {res.x, res.y, res.z, res.w};
            float ov[4];
            #pragma unroll
            for (int oo = 0; oo < 4; ++oo) {
                const float y = fmaf(a[oo][j], sc[oo], bi[oo]);
                const float h = 0.5f * (v[oo][j] + y);     // v + (y-v)/tau, tau=2
                const bool fire = (h >= 1.0f);
                v[oo][j] = fire ? 0.0f : h;                // hard reset
                ov[oo] = rr[oo] + (fire ? 1.0f : 0.0f);
            }
            ((float4*)out)[(l * NTB + n) * 32 + q4] =
                make_float4(ov[0], ov[1], ov[2], ov[3]);
        }
    };

    #pragma unroll 1
    for (int tp = 0; tp < 2; ++tp) {
        const int n0 = (tp * 2) * 32 + b;
        const int n1 = n0 + 32;

        float a0[4][JT], a1[4][JT];
        #pragma unroll
        for (int oo = 0; oo < 4; ++oo)
            #pragma unroll
            for (int j = 0; j < JT; ++j) { a0[oo][j] = 0.f; a1[oo][j] = 0.f; }

        #pragma unroll 1
        for (int half = 0; half < 2; ++half) {
            // ---- stage both n's x chunks (straight-line) ----
            const int cb = half * 16;   // chunk channel base, float4 units
            for (int idx = tid; idx < NP * 16; idx += 256) {
                const int p = idx >> 4, c = idx & 15;
                const int ll = l0 - 1 + p;
                float4 v0 = make_float4(0.f, 0.f, 0.f, 0.f);
                float4 v1 = make_float4(0.f, 0.f, 0.f, 0.f);
                if (ll >= 0 && ll < L) {
                    v0 = x4[(ll * NTB + n0) * 32 + cb + c];
                    v1 = x4[(ll * NTB + n1) * 32 + cb + c];
                }
                ((float4*)(&xs[0][0]))[p * 16 + c] = v0;
                ((float4*)(&xs[1][0]))[p * 16 + c] = v1;
            }
            __syncthreads();   // xs + current ws buffer ready

            #pragma unroll 1
            for (int itl = 0; itl < 8; ++itl) {
                const int it  = half * 8 + itl;    // global weight tile
                const int itn = (it + 1) & 15;     // wrap: next pass tile0 free
                // ---- issue next tile's global loads (unconditional) ----
                float4 wp[3];
                #pragma unroll
                for (int r = 0; r < 3; ++r)
                    wp[r] = *((const float4*)(w + wgoff[r] + itn * 24));

                const float* wsb = ws[it & 1];
                #pragma unroll
                for (int i4 = 0; i4 < 2; ++i4) {
                    float4 W0[4], W1[4], W2[4];
                    #pragma unroll
                    for (int oo = 0; oo < 4; ++oo) {
                        const float* wpt = wsb + ((oo * 6 + i4 * 3) * 32 + q4) * 4;
                        W0[oo] = *((const float4*)(wpt));
                        W1[oo] = *((const float4*)(wpt + 128));
                        W2[oo] = *((const float4*)(wpt + 256));
                    }

                    const int iic = itl * 2 + i4;                  // chunk-local group
                    const float4* xcol0 = (const float4*)(&xs[0][0]) + iic;
                    const float4* xcol1 = (const float4*)(&xs[1][0]) + iic;
                    float4 xa0 = xcol0[(p0 + 0) * 16];
                    float4 xb0 = xcol0[(p0 + 1) * 16];
                    float4 xa1 = xcol1[(p0 + 0) * 16];
                    float4 xb1 = xcol1[(p0 + 1) * 16];
                    #pragma unroll
                    for (int j = 0; j < JT; ++j) {
                        const float4 xc0 = xcol0[(p0 + j + 2) * 16];
                        const float4 xc1 = xcol1[(p0 + j + 2) * 16];
                        #pragma unroll
                        for (int oo = 0; oo < 4; ++oo) {
                            float s = a0[oo][j];
                            const float4 w0 = W0[oo], w1 = W1[oo], w2 = W2[oo];
                            s = fmaf(xa0.x, w0.x, s);   // k=0, i+0
                            s = fmaf(xa0.y, w0.w, s);   // k=0, i+1
                            s = fmaf(xa0.z, w1.z, s);   // k=0, i+2
                            s = fmaf(xa0.w, w2.y, s);   // k=0, i+3
                            s = fmaf(xb0.x, w0.y, s);   // k=1, i+0
                            s = fmaf(xb0.y, w1.x, s);   // k=1, i+1
                            s = fmaf(xb0.z, w1.w, s);   // k=1, i+2
                            s = fmaf(xb0.w, w2.z, s);   // k=1, i+3
                            s = fmaf(xc0.x, w0.z, s);   // k=2, i+0
                            s = fmaf(xc0.y, w1.y, s);   // k=2, i+1
                            s = fmaf(xc0.z, w2.x, s);   // k=2, i+2
                            s = fmaf(xc0.w, w2.w, s);   // k=2, i+3
                            a0[oo][j] = s;
                        }
                        #pragma unroll
                        for (int oo = 0; oo < 4; ++oo) {
                            float s = a1[oo][j];
                            const float4 w0 = W0[oo], w1 = W1[oo], w2 = W2[oo];
                            s = fmaf(xa1.x, w0.x, s);   // k=0, i+0
                            s = fmaf(xa1.y, w0.w, s);   // k=0, i+1
                            s = fmaf(xa1.z, w1.z, s);   // k=0, i+2
                            s = fmaf(xa1.w, w2.y, s);   // k=0, i+3
                            s = fmaf(xb1.x, w0.y, s);   // k=1, i+0
                            s = fmaf(xb1.y, w1.x, s);   // k=1, i+1
                            s = fmaf(xb1.z, w1.w, s);   // k=1, i+2
                            s = fmaf(xb1.w, w2.z, s);   // k=1, i+3
                            s = fmaf(xc1.x, w0.z, s);   // k=2, i+0
                            s = fmaf(xc1.y, w1.y, s);   // k=2, i+1
                            s = fmaf(xc1.z, w2.x, s);   // k=2, i+2
                            s = fmaf(xc1.w, w2.w, s);   // k=2, i+3
                            a1[oo][j] = s;
                        }
                        xa0 = xb0; xb0 = xc0;
                        xa1 = xb1; xb1 = xc1;
                    }
                }

                // ---- write prefetched tile into the OTHER buffer ----
                float* wsn = ws[itn & 1];
                #pragma unroll
                for (int r = 0; r < 3; ++r)
                    *((float4*)(&wsn[wloff[r]])) = wp[r];
                __syncthreads();   // one barrier per tile
            }
        }

        // ---- sequential LIF for the pair (no LDS; race-free vs next pass) ----
        epi(a0, tp * 2);
        epi(a1, tp * 2 + 1);
    }
}

extern "C" void kernel_launch(void* const* d_in, const int* in_sizes, int n_in,
                              void* d_out, int out_size, void* d_ws, size_t ws_size,
                              hipStream_t stream) {
    const float* x     = (const float*)d_in[0];
    const float* w     = (const float*)d_in[1];
    const float* gamma = (const float*)d_in[2];
    const float* beta  = (const float*)d_in[3];
    const float* mean  = (const float*)d_in[4];
    const float* var   = (const float*)d_in[5];
    float* out = (float*)d_out;

    dim3 grid((L / LT) * 32);   // 32 l-tiles x 32 b values = 1024 blocks
    dim3 block(256);
    snn_conv_lif<<<grid, block, 0, stream>>>(x, w, gamma, beta, mean, var, out);
}

// Round 16
// 614.488 us; speedup vs baseline: 1.0936x; 1.0936x over previous
//
#include <hip/hip_runtime.h>

// Fused Conv1d(k=3,pad=1) + BN(inference) + 4-step LIF + residual.
// x: (L=2048, TB=128, D=128) f32. conv_w: (D,D,3). out: (L,TB,D) f32.
//
// R18 = R17 (t-pair tile loop: two t's share every W ds_read; dbuf ws,
// 1 barrier/tile; chunked xs; R7 inner loop) with the launch bound fixed:
// empirically the allocator cap is ~256/min_waves ((256,4)->64, (256,3)->84,
// (256,2)->128 observed), so R17's ~200-reg working set spilled 830MB at
// its 128 cap. (256,1) -> cap 256, expected ~190-230 used, no spill,
// ~2 waves/SIMD (= R16's effective residency). LDS-pipe demand per FMA
// drops 1.5x vs R16; barriers 73 -> 38. Per-(o,l,t) FMA order bit-identical
// to R3/R7/R16 (absmax must stay 0.0).

constexpr int L   = 2048;
constexpr int NTB = 128;
constexpr int D   = 128;
constexpr int T   = 4;
constexpr int LT  = 64;        // l-tile per block
constexpr int NP  = LT + 2;    // 66 staged positions (halo)
constexpr int JT  = 8;         // l-positions per thread (2 groups x 8 per wave)

__global__ __launch_bounds__(256, 1)
void snn_conv_lif(const float* __restrict__ x, const float* __restrict__ w,
                  const float* __restrict__ gamma, const float* __restrict__ beta,
                  const float* __restrict__ mean, const float* __restrict__ var,
                  float* __restrict__ out) {
    __shared__ float xs[2][NP * 16 * 4];   // 2 x 16896 B: 64-ch chunk per n
    __shared__ float ws[2][768 * 4];       // 2 x 12288 B: dbuf weight tile
                                           // total 58368 B

    const int tid = threadIdx.x;
    const int b   = blockIdx.x & 31;
    const int lt  = blockIdx.x >> 5;
    const int l0  = lt * LT;
    const int q4  = tid & 31;                                 // o-quad
    const int p0  = (tid >> 6) * 16 + ((tid >> 5) & 1) * JT;  // l-group base
    const float4* x4 = (const float4*)x;

    // per-thread staging map (same transposed layout as R7/R16)
    int wgoff[3], wloff[3];
    #pragma unroll
    for (int r = 0; r < 3; ++r) {
        const int idx = tid + r * 256;
        const int qq  = idx & 31;
        const int cc  = idx >> 5;          // 0..23
        const int f   = cc >> 2;           // 0..5
        const int oo  = cc & 3;            // 0..3
        wgoff[r] = (4 * qq + oo) * (D * 3) + f * 4;          // + it*24
        wloff[r] = ((oo * 6 + f) * 32 + qq) * 4;
    }

    float sc[4], bi[4];
    {
        const float4 g4 = ((const float4*)gamma)[q4];
        const float4 b4 = ((const float4*)beta)[q4];
        const float4 m4 = ((const float4*)mean)[q4];
        const float4 v4 = ((const float4*)var)[q4];
        const float gg[4] = {g4.x, g4.y, g4.z, g4.w};
        const float bb[4] = {b4.x, b4.y, b4.z, b4.w};
        const float mm[4] = {m4.x, m4.y, m4.z, m4.w};
        const float vv[4] = {v4.x, v4.y, v4.z, v4.w};
        #pragma unroll
        for (int oo = 0; oo < 4; ++oo) {
            sc[oo] = gg[oo] / sqrtf(vv[oo] + 1e-5f);
            bi[oo] = bb[oo] - mm[oo] * sc[oo];
        }
    }

    float v[4][JT];
    #pragma unroll
    for (int oo = 0; oo < 4; ++oo)
        #pragma unroll
        for (int j = 0; j < JT; ++j) v[oo][j] = 0.f;

    // ---- prologue: stage weight tile 0 into buf 0 ----
    #pragma unroll
    for (int r = 0; r < 3; ++r)
        *((float4*)(&ws[0][wloff[r]])) = *((const float4*)(w + wgoff[r]));

    // epilogue helper: BN + LIF step for one t from one acc array (static refs)
    auto epi = [&](const float (&a)[4][JT], int t) {
        const int n = t * 32 + b;
        #pragma unroll
        for (int j = 0; j < JT; ++j) {
            const int l = l0 + p0 + j;
            const float4 res = x4[(l * NTB + n) * 32 + q4];
            const float rr[4] = {res.x, res.y, res.z, res.w};
            float ov[4];
            #pragma unroll
            for (int oo = 0; oo < 4; ++oo) {
                const float y = fmaf(a[oo][j], sc[oo], bi[oo]);
                const float h = 0.5f * (v[oo][j] + y);     // v + (y-v)/tau, tau=2
                const bool fire = (h >= 1.0f);
                v[oo][j] = fire ? 0.0f : h;                // hard reset
                ov[oo] = rr[oo] + (fire ? 1.0f : 0.0f);
            }
            ((float4*)out)[(l * NTB + n) * 32 + q4] =
                make_float4(ov[0], ov[1], ov[2], ov[3]);
        }
    };

    #pragma unroll 1
    for (int tp = 0; tp < 2; ++tp) {
        const int n0 = (tp * 2) * 32 + b;
        const int n1 = n0 + 32;

        float a0[4][JT], a1[4][JT];
        #pragma unroll
        for (int oo = 0; oo < 4; ++oo)
            #pragma unroll
            for (int j = 0; j < JT; ++j) { a0[oo][j] = 0.f; a1[oo][j] = 0.f; }

        #pragma unroll 1
        for (int half = 0; half < 2; ++half) {
            // ---- stage both n's x chunks (straight-line) ----
            const int cb = half * 16;   // chunk channel base, float4 units
            for (int idx = tid; idx < NP * 16; idx += 256) {
                const int p = idx >> 4, c = idx & 15;
                const int ll = l0 - 1 + p;
                float4 v0 = make_float4(0.f, 0.f, 0.f, 0.f);
                float4 v1 = make_float4(0.f, 0.f, 0.f, 0.f);
                if (ll >= 0 && ll < L) {
                    v0 = x4[(ll * NTB + n0) * 32 + cb + c];
                    v1 = x4[(ll * NTB + n1) * 32 + cb + c];
                }
                ((float4*)(&xs[0][0]))[p * 16 + c] = v0;
                ((float4*)(&xs[1][0]))[p * 16 + c] = v1;
            }
            __syncthreads();   // xs + current ws buffer ready

            #pragma unroll 1
            for (int itl = 0; itl < 8; ++itl) {
                const int it  = half * 8 + itl;    // global weight tile
                const int itn = (it + 1) & 15;     // wrap: next pass tile0 free
                // ---- issue next tile's global loads (unconditional) ----
                float4 wp[3];
                #pragma unroll
                for (int r = 0; r < 3; ++r)
                    wp[r] = *((const float4*)(w + wgoff[r] + itn * 24));

                const float* wsb = ws[it & 1];
                #pragma unroll
                for (int i4 = 0; i4 < 2; ++i4) {
                    float4 W0[4], W1[4], W2[4];
                    #pragma unroll
                    for (int oo = 0; oo < 4; ++oo) {
                        const float* wpt = wsb + ((oo * 6 + i4 * 3) * 32 + q4) * 4;
                        W0[oo] = *((const float4*)(wpt));
                        W1[oo] = *((const float4*)(wpt + 128));
                        W2[oo] = *((const float4*)(wpt + 256));
                    }

                    const int iic = itl * 2 + i4;                  // chunk-local group
                    const float4* xcol0 = (const float4*)(&xs[0][0]) + iic;
                    const float4* xcol1 = (const float4*)(&xs[1][0]) + iic;
                    float4 xa0 = xcol0[(p0 + 0) * 16];
                    float4 xb0 = xcol0[(p0 + 1) * 16];
                    float4 xa1 = xcol1[(p0 + 0) * 16];
                    float4 xb1 = xcol1[(p0 + 1) * 16];
                    #pragma unroll
                    for (int j = 0; j < JT; ++j) {
                        const float4 xc0 = xcol0[(p0 + j + 2) * 16];
                        const float4 xc1 = xcol1[(p0 + j + 2) * 16];
                        #pragma unroll
                        for (int oo = 0; oo < 4; ++oo) {
                            float s = a0[oo][j];
                            const float4 w0 = W0[oo], w1 = W1[oo], w2 = W2[oo];
                            s = fmaf(xa0.x, w0.x, s);   // k=0, i+0
                            s = fmaf(xa0.y, w0.w, s);   // k=0, i+1
                            s = fmaf(xa0.z, w1.z, s);   // k=0, i+2
                            s = fmaf(xa0.w, w2.y, s);   // k=0, i+3
                            s = fmaf(xb0.x, w0.y, s);   // k=1, i+0
                            s = fmaf(xb0.y, w1.x, s);   // k=1, i+1
                            s = fmaf(xb0.z, w1.w, s);   // k=1, i+2
                            s = fmaf(xb0.w, w2.z, s);   // k=1, i+3
                            s = fmaf(xc0.x, w0.z, s);   // k=2, i+0
                            s = fmaf(xc0.y, w1.y, s);   // k=2, i+1
                            s = fmaf(xc0.z, w2.x, s);   // k=2, i+2
                            s = fmaf(xc0.w, w2.w, s);   // k=2, i+3
                            a0[oo][j] = s;
                        }
                        #pragma unroll
                        for (int oo = 0; oo < 4; ++oo) {
                            float s = a1[oo][j];
                            const float4 w0 = W0[oo], w1 = W1[oo], w2 = W2[oo];
                            s = fmaf(xa1.x, w0.x, s);   // k=0, i+0
                            s = fmaf(xa1.y, w0.w, s);   // k=0, i+1
                            s = fmaf(xa1.z, w1.z, s);   // k=0, i+2
                            s = fmaf(xa1.w, w2.y, s);   // k=0, i+3
                            s = fmaf(xb1.x, w0.y, s);   // k=1, i+0
                            s = fmaf(xb1.y, w1.x, s);   // k=1, i+1
                            s = fmaf(xb1.z, w1.w, s);   // k=1, i+2
                            s = fmaf(xb1.w, w2.z, s);   // k=1, i+3
                            s = fmaf(xc1.x, w0.z, s);   // k=2, i+0
                            s = fmaf(xc1.y, w1.y, s);   // k=2, i+1
                            s = fmaf(xc1.z, w2.x, s);   // k=2, i+2
                            s = fmaf(xc1.w, w2.w, s);   // k=2, i+3
                            a1[oo][j] = s;
                        }
                        xa0 = xb0; xb0 = xc0;
                        xa1 = xb1; xb1 = xc1;
                    }
                }

                // ---- write prefetched tile into the OTHER buffer ----
                float* wsn = ws[itn & 1];
                #pragma unroll
                for (int r = 0; r < 3; ++r)
                    *((float4*)(&wsn[wloff[r]])) = wp[r];
                __syncthreads();   // one barrier per tile
            }
        }

        // ---- sequential LIF for the pair (no LDS; race-free vs next pass) ----
        epi(a0, tp * 2);
        epi(a1, tp * 2 + 1);
    }
}

extern "C" void kernel_launch(void* const* d_in, const int* in_sizes, int n_in,
                              void* d_out, int out_size, void* d_ws, size_t ws_size,
                              hipStream_t stream) {
    const float* x     = (const float*)d_in[0];
    const float* w     = (const float*)d_in[1];
    const float* gamma = (const float*)d_in[2];
    const float* beta  = (const float*)d_in[3];
    const float* mean  = (const float*)d_in[4];
    const float* var   = (const float*)d_in[5];
    float* out = (float*)d_out;

    dim3 grid((L / LT) * 32);   // 32 l-tiles x 32 b values = 1024 blocks
    dim3 block(256);
    snn_conv_lif<<<grid, block, 0, stream>>>(x, w, gamma, beta, mean, var, out);
}

// Round 17
// 595.164 us; speedup vs baseline: 1.1291x; 1.0325x over previous
//
#include <hip/hip_runtime.h>

// Fused Conv1d(k=3,pad=1) + BN(inference) + 4-step LIF + residual.
// x: (L=2048, TB=128, D=128) f32. conv_w: (D,D,3). out: (L,TB,D) f32.
//
// R19 = R18 (t-pair: two t's share every W ds_read; dbuf ws, 1 barrier/tile;
// R7 inner loop; (256,1) bounds -> 168 VGPR, zero spill) with xs QUARTERED:
// 32-channel chunks staged 4x per t-pair (each covers 4 weight tiles).
// LDS 58.4 -> 41.5 KB = R16's proven 2.2-block/CU footprint (R18's 58 KB
// collapsed residency to 1 block -> 524us despite clean codegen).
// Per-CU pipe balance at 2 blocks: LDS ~6144 cyc/tile ~= FMA ~6144 —
// both ~100% vs R16's LDS at 137% of FMA.
// Per-(o,l,t) FMA order bit-identical to R3/R7/R16 (absmax must stay 0.0).

constexpr int L   = 2048;
constexpr int NTB = 128;
constexpr int D   = 128;
constexpr int T   = 4;
constexpr int LT  = 64;        // l-tile per block
constexpr int NP  = LT + 2;    // 66 staged positions (halo)
constexpr int JT  = 8;         // l-positions per thread (2 groups x 8 per wave)

__global__ __launch_bounds__(256, 1)
void snn_conv_lif(const float* __restrict__ x, const float* __restrict__ w,
                  const float* __restrict__ gamma, const float* __restrict__ beta,
                  const float* __restrict__ mean, const float* __restrict__ var,
                  float* __restrict__ out) {
    __shared__ float xs[2][NP * 8 * 4];    // 2 x 8448 B: 32-ch quarter per n
    __shared__ float ws[2][768 * 4];       // 2 x 12288 B: dbuf weight tile
                                           // total 41472 B (= R16 footprint)

    const int tid = threadIdx.x;
    const int b   = blockIdx.x & 31;
    const int lt  = blockIdx.x >> 5;
    const int l0  = lt * LT;
    const int q4  = tid & 31;                                 // o-quad
    const int p0  = (tid >> 6) * 16 + ((tid >> 5) & 1) * JT;  // l-group base
    const float4* x4 = (const float4*)x;

    // per-thread staging map (same transposed layout as R7/R16)
    int wgoff[3], wloff[3];
    #pragma unroll
    for (int r = 0; r < 3; ++r) {
        const int idx = tid + r * 256;
        const int qq  = idx & 31;
        const int cc  = idx >> 5;          // 0..23
        const int f   = cc >> 2;           // 0..5
        const int oo  = cc & 3;            // 0..3
        wgoff[r] = (4 * qq + oo) * (D * 3) + f * 4;          // + it*24
        wloff[r] = ((oo * 6 + f) * 32 + qq) * 4;
    }

    float sc[4], bi[4];
    {
        const float4 g4 = ((const float4*)gamma)[q4];
        const float4 b4 = ((const float4*)beta)[q4];
        const float4 m4 = ((const float4*)mean)[q4];
        const float4 v4 = ((const float4*)var)[q4];
        const float gg[4] = {g4.x, g4.y, g4.z, g4.w};
        const float bb[4] = {b4.x, b4.y, b4.z, b4.w};
        const float mm[4] = {m4.x, m4.y, m4.z, m4.w};
        const float vv[4] = {v4.x, v4.y, v4.z, v4.w};
        #pragma unroll
        for (int oo = 0; oo < 4; ++oo) {
            sc[oo] = gg[oo] / sqrtf(vv[oo] + 1e-5f);
            bi[oo] = bb[oo] - mm[oo] * sc[oo];
        }
    }

    float v[4][JT];
    #pragma unroll
    for (int oo = 0; oo < 4; ++oo)
        #pragma unroll
        for (int j = 0; j < JT; ++j) v[oo][j] = 0.f;

    // ---- prologue: stage weight tile 0 into buf 0 ----
    #pragma unroll
    for (int r = 0; r < 3; ++r)
        *((float4*)(&ws[0][wloff[r]])) = *((const float4*)(w + wgoff[r]));

    // epilogue helper: BN + LIF step for one t from one acc array (static refs)
    auto epi = [&](const float (&a)[4][JT], int t) {
        const int n = t * 32 + b;
        #pragma unroll
        for (int j = 0; j < JT; ++j) {
            const int l = l0 + p0 + j;
            const float4 res = x4[(l * NTB + n) * 32 + q4];
            const float rr[4] = {res.x, res.y, res.z, res.w};
            float ov[4];
            #pragma unroll
            for (int oo = 0; oo < 4; ++oo) {
                const float y = fmaf(a[oo][j], sc[oo], bi[oo]);
                const float h = 0.5f * (v[oo][j] + y);     // v + (y-v)/tau, tau=2
                const bool fire = (h >= 1.0f);
                v[oo][j] = fire ? 0.0f : h;                // hard reset
                ov[oo] = rr[oo] + (fire ? 1.0f : 0.0f);
            }
            ((float4*)out)[(l * NTB + n) * 32 + q4] =
                make_float4(ov[0], ov[1], ov[2], ov[3]);
        }
    };

    #pragma unroll 1
    for (int tp = 0; tp < 2; ++tp) {
        const int n0 = (tp * 2) * 32 + b;
        const int n1 = n0 + 32;

        float a0[4][JT], a1[4][JT];
        #pragma unroll
        for (int oo = 0; oo < 4; ++oo)
            #pragma unroll
            for (int j = 0; j < JT; ++j) { a0[oo][j] = 0.f; a1[oo][j] = 0.f; }

        #pragma unroll 1
        for (int qtr = 0; qtr < 4; ++qtr) {
            // ---- stage both n's 32-ch x quarter (straight-line) ----
            const int cb = qtr * 8;     // quarter channel base, float4 units
            #pragma unroll 1
            for (int idx = tid; idx < NP * 8; idx += 256) {
                const int p = idx >> 3, c = idx & 7;
                const int ll = l0 - 1 + p;
                float4 v0 = make_float4(0.f, 0.f, 0.f, 0.f);
                float4 v1 = make_float4(0.f, 0.f, 0.f, 0.f);
                if (ll >= 0 && ll < L) {
                    v0 = x4[(ll * NTB + n0) * 32 + cb + c];
                    v1 = x4[(ll * NTB + n1) * 32 + cb + c];
                }
                ((float4*)(&xs[0][0]))[p * 8 + c] = v0;
                ((float4*)(&xs[1][0]))[p * 8 + c] = v1;
            }
            __syncthreads();   // xs + current ws buffer ready

            #pragma unroll 1
            for (int itl = 0; itl < 4; ++itl) {
                const int it  = qtr * 4 + itl;     // global weight tile
                const int itn = (it + 1) & 15;     // wrap: next pass tile0 free
                // ---- issue next tile's global loads (unconditional) ----
                float4 wp[3];
                #pragma unroll
                for (int r = 0; r < 3; ++r)
                    wp[r] = *((const float4*)(w + wgoff[r] + itn * 24));

                const float* wsb = ws[it & 1];
                #pragma unroll
                for (int i4 = 0; i4 < 2; ++i4) {
                    float4 W0[4], W1[4], W2[4];
                    #pragma unroll
                    for (int oo = 0; oo < 4; ++oo) {
                        const float* wpt = wsb + ((oo * 6 + i4 * 3) * 32 + q4) * 4;
                        W0[oo] = *((const float4*)(wpt));
                        W1[oo] = *((const float4*)(wpt + 128));
                        W2[oo] = *((const float4*)(wpt + 256));
                    }

                    const int iic = itl * 2 + i4;                  // quarter-local group
                    const float4* xcol0 = (const float4*)(&xs[0][0]) + iic;
                    const float4* xcol1 = (const float4*)(&xs[1][0]) + iic;
                    float4 xa0 = xcol0[(p0 + 0) * 8];
                    float4 xb0 = xcol0[(p0 + 1) * 8];
                    float4 xa1 = xcol1[(p0 + 0) * 8];
                    float4 xb1 = xcol1[(p0 + 1) * 8];
                    #pragma unroll
                    for (int j = 0; j < JT; ++j) {
                        const float4 xc0 = xcol0[(p0 + j + 2) * 8];
                        const float4 xc1 = xcol1[(p0 + j + 2) * 8];
                        #pragma unroll
                        for (int oo = 0; oo < 4; ++oo) {
                            float s = a0[oo][j];
                            const float4 w0 = W0[oo], w1 = W1[oo], w2 = W2[oo];
                            s = fmaf(xa0.x, w0.x, s);   // k=0, i+0
                            s = fmaf(xa0.y, w0.w, s);   // k=0, i+1
                            s = fmaf(xa0.z, w1.z, s);   // k=0, i+2
                            s = fmaf(xa0.w, w2.y, s);   // k=0, i+3
                            s = fmaf(xb0.x, w0.y, s);   // k=1, i+0
                            s = fmaf(xb0.y, w1.x, s);   // k=1, i+1
                            s = fmaf(xb0.z, w1.w, s);   // k=1, i+2
                            s = fmaf(xb0.w, w2.z, s);   // k=1, i+3
                            s = fmaf(xc0.x, w0.z, s);   // k=2, i+0
                            s = fmaf(xc0.y, w1.y, s);   // k=2, i+1
                            s = fmaf(xc0.z, w2.x, s);   // k=2, i+2
                            s = fmaf(xc0.w, w2.w, s);   // k=2, i+3
                            a0[oo][j] = s;
                        }
                        #pragma unroll
                        for (int oo = 0; oo < 4; ++oo) {
                            float s = a1[oo][j];
                            const float4 w0 = W0[oo], w1 = W1[oo], w2 = W2[oo];
                            s = fmaf(xa1.x, w0.x, s);   // k=0, i+0
                            s = fmaf(xa1.y, w0.w, s);   // k=0, i+1
                            s = fmaf(xa1.z, w1.z, s);   // k=0, i+2
                            s = fmaf(xa1.w, w2.y, s);   // k=0, i+3
                            s = fmaf(xb1.x, w0.y, s);   // k=1, i+0
                            s = fmaf(xb1.y, w1.x, s);   // k=1, i+1
                            s = fmaf(xb1.z, w1.w, s);   // k=1, i+2
                            s = fmaf(xb1.w, w2.z, s);   // k=1, i+3
                            s = fmaf(xc1.x, w0.z, s);   // k=2, i+0
                            s = fmaf(xc1.y, w1.y, s);   // k=2, i+1
                            s = fmaf(xc1.z, w2.x, s);   // k=2, i+2
                            s = fmaf(xc1.w, w2.w, s);   // k=2, i+3
                            a1[oo][j] = s;
                        }
                        xa0 = xb0; xb0 = xc0;
                        xa1 = xb1; xb1 = xc1;
                    }
                }

                // ---- write prefetched tile into the OTHER buffer ----
                float* wsn = ws[itn & 1];
                #pragma unroll
                for (int r = 0; r < 3; ++r)
                    *((float4*)(&wsn[wloff[r]])) = wp[r];
                __syncthreads();   // one barrier per tile
            }
        }

        // ---- sequential LIF for the pair (no LDS; race-free vs next pass) ----
        epi(a0, tp * 2);
        epi(a1, tp * 2 + 1);
    }
}

extern "C" void kernel_launch(void* const* d_in, const int* in_sizes, int n_in,
                              void* d_out, int out_size, void* d_ws, size_t ws_size,
                              hipStream_t stream) {
    const float* x     = (const float*)d_in[0];
    const float* w     = (const float*)d_in[1];
    const float* gamma = (const float*)d_in[2];
    const float* beta  = (const float*)d_in[3];
    const float* mean  = (const float*)d_in[4];
    const float* var   = (const float*)d_in[5];
    float* out = (float*)d_out;

    dim3 grid((L / LT) * 32);   // 32 l-tiles x 32 b values = 1024 blocks
    dim3 block(256);
    snn_conv_lif<<<grid, block, 0, stream>>>(x, w, gamma, beta, mean, var, out);
}